// Round 6
// baseline (5241.686 us; speedup 1.0000x reference)
//
#include <hip/hip_runtime.h>
#include <stdint.h>

// LSTMClassifier on MI355X — persistent flag-synced scan (round 6).
// Identical to round 5 except the release fence: __hip_atomic_fence does not
// exist in this ROCm; use __threadfence() (agent-scope) + release store,
// which compiled in round 2.
//
// Workspace (48.2 MiB):
//   [0,256)          int flags[64]              (memset 0 per launch)
//   [256, +33.6MB)   bf16 h_buf[513][64][512]   (h_buf[0] memset 0)
//   [+,   +16.8MB)   bf16 e_seq[32768][256]

#define EMB   256
#define HID   512
#define NOUT  18
#define BATCH 64
#define SEQ   512

typedef __attribute__((ext_vector_type(8))) short bf16x8;
typedef __attribute__((ext_vector_type(4))) float floatx4;

__device__ inline float bf2f(short u) {
    union { float f; uint32_t i; } v;
    v.i = ((uint32_t)(uint16_t)u) << 16;
    return v.f;
}
__device__ inline short f2bf(float f) {
    union { float f; uint32_t i; } v; v.f = f;
    uint32_t r = v.i + 0x7fffu + ((v.i >> 16) & 1u);   // RNE
    return (short)(r >> 16);
}
__device__ inline float sigm(float x) { return 1.f / (1.f + __expf(-x)); }
__device__ inline float tanh_fast(float x) {
    float xc = fminf(fmaxf(x, -15.f), 15.f);
    float e  = __expf(2.f * xc);
    return (e - 1.f) / (e + 1.f);
}

// Detect packed-bf16 vs fp32 float tensors from emb's bit patterns (verified
// working in round 4 — do not remove).
__device__ inline bool detect_bf16(const void* emb_raw) {
    const uint32_t* w = (const uint32_t*)emb_raw;
    int votes = 0;
    #pragma unroll
    for (int i = 0; i < 8; i++) {
        uint32_t e = (w[i] >> 7) & 0xFFu;
        votes += (e >= 110u && e <= 135u) ? 1 : 0;
    }
    return votes >= 6;
}
__device__ inline float rd(const void* p, int idx, bool isbf) {
    return isbf ? bf2f(((const short*)p)[idx]) : ((const float*)p)[idx];
}

// ---------------------------------------------------------------------------
// K0: e_seq[u][k] = emb[x[u&63][u>>6]][k] (bf16 out), u = s*64+b.
// ---------------------------------------------------------------------------
__global__ __launch_bounds__(256) void k0_gather(
    const int* __restrict__ x, const void* __restrict__ emb,
    short* __restrict__ eseq)
{
    const bool isbf = detect_bf16(emb);
    const int u0 = blockIdx.x * 32;
    #pragma unroll
    for (int it = 0; it < 4; it++) {
        int idx = it * 256 + threadIdx.x;          // 0..1023
        int u   = u0 + (idx >> 5);
        int ch  = (idx & 31) * 8;
        int tok = x[(u & 63) * SEQ + (u >> 6)];
        bf16x8 v;
        if (isbf) {
            v = *(const bf16x8*)((const short*)emb + (size_t)tok * EMB + ch);
        } else {
            const float* src = (const float*)emb + (size_t)tok * EMB + ch;
            #pragma unroll
            for (int j = 0; j < 8; j++) v[j] = f2bf(src[j]);
        }
        *(bf16x8*)(eseq + (size_t)u * EMB + ch) = v;
    }
}

// ---------------------------------------------------------------------------
// K2: persistent LSTM scan. 64 wgs; wg g owns h/gate columns [8g, 8g+8).
// LDS Ws row n (q=n>>3, j=n&7): cols [0,512)=W_hh row q*512+g*8+j,
// cols [512,768)=W_ih same row. Staged ONCE. c lives in LDS.
// ---------------------------------------------------------------------------
__global__ __launch_bounds__(256) void k2_lstm(
    const void* __restrict__ w_hh, const void* __restrict__ w_ih,
    const void* __restrict__ b_ih, const void* __restrict__ b_hh,
    const void* __restrict__ emb, const short* __restrict__ eseq,
    short* __restrict__ hbuf, int* __restrict__ flags)
{
    __shared__ short Ws[32][784];     // 768 + 16 pad
    __shared__ float gates[64][33];
    __shared__ float cst[64][8];
    __shared__ float bias[32];

    const bool isbf = detect_bf16(emb);
    const int t    = threadIdx.x;
    const int g    = blockIdx.x;      // 0..63
    const int lane = t & 63;
    const int w    = t >> 6;
    const int col  = lane & 15;
    const int quad = lane >> 4;

    // ---- one-time staging ----
    #pragma unroll
    for (int it = 0; it < 8; it++) {                 // W_hh slice 32x512
        int idx = it * 256 + t;
        int n = idx >> 6, ch = (idx & 63) * 8;
        int grow = (n >> 3) * HID + g * 8 + (n & 7);
        bf16x8 v;
        if (isbf) {
            v = *(const bf16x8*)((const short*)w_hh + (size_t)grow * HID + ch);
        } else {
            const float* src = (const float*)w_hh + (size_t)grow * HID + ch;
            #pragma unroll
            for (int j = 0; j < 8; j++) v[j] = f2bf(src[j]);
        }
        *(bf16x8*)&Ws[n][ch] = v;
    }
    #pragma unroll
    for (int it = 0; it < 4; it++) {                 // W_ih slice 32x256
        int idx = it * 256 + t;
        int n = idx >> 5, ch = (idx & 31) * 8;
        int grow = (n >> 3) * HID + g * 8 + (n & 7);
        bf16x8 v;
        if (isbf) {
            v = *(const bf16x8*)((const short*)w_ih + (size_t)grow * EMB + ch);
        } else {
            const float* src = (const float*)w_ih + (size_t)grow * EMB + ch;
            #pragma unroll
            for (int j = 0; j < 8; j++) v[j] = f2bf(src[j]);
        }
        *(bf16x8*)&Ws[n][HID + ch] = v;
    }
    if (t < 32) {
        int grow = (t >> 3) * HID + g * 8 + (t & 7);
        bias[t] = rd(b_ih, grow, isbf) + rd(b_hh, grow, isbf);
    }
    #pragma unroll
    for (int half = 0; half < 2; half++)
        ((float*)cst)[half * 256 + t] = 0.f;
    __syncthreads();

    // ---- scan ----
    for (int step = 0; step < SEQ; step++) {
        // acquire: h_buf[step] complete from all 64 wgs (lane i watches wg i)
        if (w == 0) {
            while (__hip_atomic_load(&flags[lane], __ATOMIC_ACQUIRE,
                                     __HIP_MEMORY_SCOPE_AGENT) < step)
                __builtin_amdgcn_s_sleep(4);
        }
        __syncthreads();

        // A fragments: batch rows (wave w -> rows 16w..16w+15), 24 k-chunks
        const short* hrow = hbuf + (size_t)step * (BATCH * HID)
                          + (w * 16 + col) * HID + quad * 8;
        const short* erow = eseq + ((size_t)step * BATCH + (w * 16 + col)) * EMB
                          + quad * 8;
        bf16x8 afr[24];
        #pragma unroll
        for (int kk = 0; kk < 16; kk++)
            afr[kk] = *(const bf16x8*)(hrow + kk * 32);
        #pragma unroll
        for (int kk = 0; kk < 8; kk++)
            afr[16 + kk] = *(const bf16x8*)(erow + kk * 32);

        floatx4 acc0 = (floatx4){0.f, 0.f, 0.f, 0.f};
        floatx4 acc1 = (floatx4){0.f, 0.f, 0.f, 0.f};
        #pragma unroll
        for (int kk = 0; kk < 24; kk++) {
            bf16x8 b0 = *(bf16x8*)&Ws[col][kk * 32 + quad * 8];
            bf16x8 b1 = *(bf16x8*)&Ws[16 + col][kk * 32 + quad * 8];
            acc0 = __builtin_amdgcn_mfma_f32_16x16x32_bf16(afr[kk], b0, acc0, 0, 0, 0);
            acc1 = __builtin_amdgcn_mfma_f32_16x16x32_bf16(afr[kk], b1, acc1, 0, 0, 0);
        }
        #pragma unroll
        for (int r = 0; r < 4; r++) {
            gates[w * 16 + quad * 4 + r][col]      = acc0[r];
            gates[w * 16 + quad * 4 + r][16 + col] = acc1[r];
        }
        __syncthreads();

        // postprocess: 512 (m,j) cells, 2 per thread; h -> hbuf[step+1]
        #pragma unroll
        for (int half = 0; half < 2; half++) {
            int idx = half * 256 + t;
            int m = idx >> 3, j = idx & 7;
            float iv = sigm(gates[m][j]      + bias[j]);
            float fv = sigm(gates[m][8 + j]  + bias[8 + j]);
            float gv = tanh_fast(gates[m][16 + j] + bias[16 + j]);
            float ov = sigm(gates[m][24 + j] + bias[24 + j]);
            float c  = fv * cst[m][j] + iv * gv;
            cst[m][j] = c;
            float h  = ov * tanh_fast(c);
            hbuf[(size_t)(step + 1) * (BATCH * HID) + m * HID + g * 8 + j] = f2bf(h);
        }
        // barrier ensures every thread's h-store has issued; threadfence below
        // (agent scope) makes them visible across XCDs before the flag.
        __syncthreads();

        if (t == 0) {
            __threadfence();
            __hip_atomic_store(&flags[g], step + 1, __ATOMIC_RELEASE,
                               __HIP_MEMORY_SCOPE_AGENT);
        }
    }
}

// ---------------------------------------------------------------------------
// K3: logits = h_seq * W_fc^T + b_fc -> log_softmax(18). One token per thread.
// ---------------------------------------------------------------------------
__global__ __launch_bounds__(256) void k3_logits(
    const short* __restrict__ hbuf, const void* __restrict__ w_fc,
    const void* __restrict__ b_fc, const void* __restrict__ emb,
    void* __restrict__ out)
{
    __shared__ float Wf[NOUT][516];
    const bool isbf = detect_bf16(emb);
    const int t = threadIdx.x;
    for (int idx = t; idx < NOUT * 64; idx += 256) {
        int o = idx >> 6, ch = (idx & 63) * 8;
        #pragma unroll
        for (int j = 0; j < 8; j++)
            Wf[o][ch + j] = rd(w_fc, o * HID + ch + j, isbf);
    }
    __syncthreads();

    int u = blockIdx.x * 256 + t;              // u = s*64+b
    const short* hp = hbuf + (size_t)(u + BATCH) * HID;

    float acc[NOUT];
    #pragma unroll
    for (int o = 0; o < NOUT; o++) acc[o] = rd(b_fc, o, isbf);

    for (int ch = 0; ch < HID; ch += 8) {
        bf16x8 h8 = *(const bf16x8*)(hp + ch);
        float hf[8];
        #pragma unroll
        for (int j = 0; j < 8; j++) hf[j] = bf2f(h8[j]);
        #pragma unroll
        for (int o = 0; o < NOUT; o++) {
            floatx4 wa = *(const floatx4*)&Wf[o][ch];
            floatx4 wb = *(const floatx4*)&Wf[o][ch + 4];
            acc[o] += hf[0] * wa[0] + hf[1] * wa[1] + hf[2] * wa[2] + hf[3] * wa[3]
                    + hf[4] * wb[0] + hf[5] * wb[1] + hf[6] * wb[2] + hf[7] * wb[3];
        }
    }

    float mx = acc[0];
    #pragma unroll
    for (int o = 1; o < NOUT; o++) mx = fmaxf(mx, acc[o]);
    float s = 0.f;
    #pragma unroll
    for (int o = 0; o < NOUT; o++) s += __expf(acc[o] - mx);
    float lse = mx + __logf(s);

    int b = u & 63, sq = u >> 6;
    size_t base = (size_t)b * (SEQ * NOUT) + (size_t)sq * NOUT;
    if (isbf) {
        short* op = (short*)out + base;
        #pragma unroll
        for (int o = 0; o < NOUT; o++) op[o] = f2bf(acc[o] - lse);
    } else {
        float* op = (float*)out + base;
        #pragma unroll
        for (int o = 0; o < NOUT; o++) op[o] = acc[o] - lse;
    }
}

// ---------------------------------------------------------------------------
extern "C" void kernel_launch(void* const* d_in, const int* in_sizes, int n_in,
                              void* d_out, int out_size, void* d_ws, size_t ws_size,
                              hipStream_t stream) {
    const int*  x   = (const int*)d_in[0];
    const void* emb = d_in[1];
    const void* wih = d_in[2];
    const void* whh = d_in[3];
    const void* bih = d_in[4];
    const void* bhh = d_in[5];
    const void* wfc = d_in[6];
    const void* bfc = d_in[7];

    char*  ws    = (char*)d_ws;
    int*   flags = (int*)ws;
    short* hbuf  = (short*)(ws + 256);
    short* eseq  = (short*)(ws + 256 + (size_t)(SEQ + 1) * BATCH * HID * 2);

    (void)hipMemsetAsync(flags, 0, 256, stream);                    // flags = 0
    (void)hipMemsetAsync(hbuf, 0, (size_t)BATCH * HID * 2, stream); // h_0 = 0

    k0_gather<<<1024, 256, 0, stream>>>(x, emb, eseq);
    k2_lstm<<<64, 256, 0, stream>>>(whh, wih, bih, bhh, emb, eseq, hbuf, flags);
    k3_logits<<<128, 256, 0, stream>>>(hbuf, wfc, bfc, emb, d_out);
}

// Round 7
// 3652.929 us; speedup vs baseline: 1.4349x; 1.4349x over previous
//
#include <hip/hip_runtime.h>
#include <stdint.h>

// LSTMClassifier on MI355X — round 7: coherent-exchange persistent scan.
// Round 6 (threadfence + acquire-spin) was correct but 9.9 us/step: agent
// release/acquire lowers to whole-L2 writeback (buffer_wbl2) / invalidate
// (buffer_inv) on gfx950, and 64 wgs spin-polling with acquire hammered the
// L2 every step. This round removes ALL cache-maintenance ops from the loop:
// every cross-wg datum (h words, arrival counters) is accessed only through
// agent-scope RELAXED atomics (coherent point, no flush), ordering by
// __syncthreads vmcnt-drain + control dependency.
//
// Workspace (48.2 MiB):
//   [0,4096)         int cnt[513]               (memset 0 per launch)
//   [4096, +33.6MB)  bf16 h_buf[513][64][512]   (h_buf[0] memset 0)
//   [+,   +16.8MB)   bf16 e_seq[32768][256]

#define EMB   256
#define HID   512
#define NOUT  18
#define BATCH 64
#define SEQ   512

typedef __attribute__((ext_vector_type(8))) short bf16x8;
typedef __attribute__((ext_vector_type(4))) float floatx4;

__device__ inline float bf2f(short u) {
    union { float f; uint32_t i; } v;
    v.i = ((uint32_t)(uint16_t)u) << 16;
    return v.f;
}
__device__ inline short f2bf(float f) {
    union { float f; uint32_t i; } v; v.f = f;
    uint32_t r = v.i + 0x7fffu + ((v.i >> 16) & 1u);   // RNE
    return (short)(r >> 16);
}
__device__ inline float sigm(float x) { return 1.f / (1.f + __expf(-x)); }
__device__ inline float tanh_fast(float x) {
    float xc = fminf(fmaxf(x, -15.f), 15.f);
    float e  = __expf(2.f * xc);
    return (e - 1.f) / (e + 1.f);
}

// Detect packed-bf16 vs fp32 float tensors (verified round 4 — keep).
__device__ inline bool detect_bf16(const void* emb_raw) {
    const uint32_t* w = (const uint32_t*)emb_raw;
    int votes = 0;
    #pragma unroll
    for (int i = 0; i < 8; i++) {
        uint32_t e = (w[i] >> 7) & 0xFFu;
        votes += (e >= 110u && e <= 135u) ? 1 : 0;
    }
    return votes >= 6;
}
__device__ inline float rd(const void* p, int idx, bool isbf) {
    return isbf ? bf2f(((const short*)p)[idx]) : ((const float*)p)[idx];
}

// ---------------------------------------------------------------------------
// K0: e_seq[u][k] = emb[x[u&63][u>>6]][k] (bf16 out), u = s*64+b.
// ---------------------------------------------------------------------------
__global__ __launch_bounds__(256) void k0_gather(
    const int* __restrict__ x, const void* __restrict__ emb,
    short* __restrict__ eseq)
{
    const bool isbf = detect_bf16(emb);
    const int u0 = blockIdx.x * 32;
    #pragma unroll
    for (int it = 0; it < 4; it++) {
        int idx = it * 256 + threadIdx.x;          // 0..1023
        int u   = u0 + (idx >> 5);
        int ch  = (idx & 31) * 8;
        int tok = x[(u & 63) * SEQ + (u >> 6)];
        bf16x8 v;
        if (isbf) {
            v = *(const bf16x8*)((const short*)emb + (size_t)tok * EMB + ch);
        } else {
            const float* src = (const float*)emb + (size_t)tok * EMB + ch;
            #pragma unroll
            for (int j = 0; j < 8; j++) v[j] = f2bf(src[j]);
        }
        *(bf16x8*)(eseq + (size_t)u * EMB + ch) = v;
    }
}

// ---------------------------------------------------------------------------
// K2: persistent LSTM scan, coherent h exchange. 64 wgs; wg g owns h/gate
// columns [8g, 8g+8). LDS Ws row n (q=n>>3, j=n&7): cols [0,512)=W_hh row
// q*512+g*8+j, cols [512,768)=W_ih same row. Staged ONCE. c in LDS.
// ---------------------------------------------------------------------------
__global__ __launch_bounds__(256) void k2_lstm(
    const void* __restrict__ w_hh, const void* __restrict__ w_ih,
    const void* __restrict__ b_ih, const void* __restrict__ b_hh,
    const void* __restrict__ emb, const short* __restrict__ eseq,
    short* __restrict__ hbuf, int* __restrict__ cnt)
{
    __shared__ short Ws[32][784];     // 768 + 16 pad
    __shared__ float gates[64][33];
    __shared__ float cst[64][8];
    __shared__ float bias[32];

    const bool isbf = detect_bf16(emb);
    const int t    = threadIdx.x;
    const int g    = blockIdx.x;      // 0..63
    const int lane = t & 63;
    const int w    = t >> 6;
    const int col  = lane & 15;
    const int quad = lane >> 4;

    // ---- one-time staging ----
    #pragma unroll
    for (int it = 0; it < 8; it++) {                 // W_hh slice 32x512
        int idx = it * 256 + t;
        int n = idx >> 6, ch = (idx & 63) * 8;
        int grow = (n >> 3) * HID + g * 8 + (n & 7);
        bf16x8 v;
        if (isbf) {
            v = *(const bf16x8*)((const short*)w_hh + (size_t)grow * HID + ch);
        } else {
            const float* src = (const float*)w_hh + (size_t)grow * HID + ch;
            #pragma unroll
            for (int j = 0; j < 8; j++) v[j] = f2bf(src[j]);
        }
        *(bf16x8*)&Ws[n][ch] = v;
    }
    #pragma unroll
    for (int it = 0; it < 4; it++) {                 // W_ih slice 32x256
        int idx = it * 256 + t;
        int n = idx >> 5, ch = (idx & 31) * 8;
        int grow = (n >> 3) * HID + g * 8 + (n & 7);
        bf16x8 v;
        if (isbf) {
            v = *(const bf16x8*)((const short*)w_ih + (size_t)grow * EMB + ch);
        } else {
            const float* src = (const float*)w_ih + (size_t)grow * EMB + ch;
            #pragma unroll
            for (int j = 0; j < 8; j++) v[j] = f2bf(src[j]);
        }
        *(bf16x8*)&Ws[n][HID + ch] = v;
    }
    if (t < 32) {
        int grow = (t >> 3) * HID + g * 8 + (t & 7);
        bias[t] = rd(b_ih, grow, isbf) + rd(b_hh, grow, isbf);
    }
    #pragma unroll
    for (int half = 0; half < 2; half++)
        ((float*)cst)[half * 256 + t] = 0.f;
    __syncthreads();

    const unsigned long long* hq = (const unsigned long long*)hbuf;

    // ---- scan ----
    for (int step = 0; step < SEQ; step++) {
        // wait: h_buf[step] complete from all 64 wgs. step 0 is pre-zeroed
        // (kernel-boundary coherent). Relaxed poll; __syncthreads below is the
        // compiler/HW ordering point; h loads themselves are coherent.
        if (step > 0 && t == 0) {
            while (__hip_atomic_load(&cnt[step], __ATOMIC_RELAXED,
                                     __HIP_MEMORY_SCOPE_AGENT) < 64)
                __builtin_amdgcn_s_sleep(1);
        }
        __syncthreads();

        // A fragments: batch rows (wave w -> rows 16w..16w+15), 24 k-chunks.
        // h chunks via coherent u64 atomic loads (bypass stale L2, no inv).
        bf16x8 afr[24];
        {
            size_t sbase = (size_t)step * (BATCH * HID)
                         + (size_t)(w * 16 + col) * HID + quad * 8;  // short idx
            size_t qbase = sbase >> 2;                               // u64 idx
            #pragma unroll
            for (int kk = 0; kk < 16; kk++) {
                union { bf16x8 v; unsigned long long q[2]; } u;
                u.q[0] = __hip_atomic_load(hq + qbase + kk * 8,
                                           __ATOMIC_RELAXED, __HIP_MEMORY_SCOPE_AGENT);
                u.q[1] = __hip_atomic_load(hq + qbase + kk * 8 + 1,
                                           __ATOMIC_RELAXED, __HIP_MEMORY_SCOPE_AGENT);
                afr[kk] = u.v;
            }
        }
        {
            const short* erow = eseq + ((size_t)step * BATCH + (w * 16 + col)) * EMB
                              + quad * 8;
            #pragma unroll
            for (int kk = 0; kk < 8; kk++)
                afr[16 + kk] = *(const bf16x8*)(erow + kk * 32);
        }

        floatx4 acc0 = (floatx4){0.f, 0.f, 0.f, 0.f};
        floatx4 acc1 = (floatx4){0.f, 0.f, 0.f, 0.f};
        #pragma unroll
        for (int kk = 0; kk < 24; kk++) {
            bf16x8 b0 = *(bf16x8*)&Ws[col][kk * 32 + quad * 8];
            bf16x8 b1 = *(bf16x8*)&Ws[16 + col][kk * 32 + quad * 8];
            acc0 = __builtin_amdgcn_mfma_f32_16x16x32_bf16(afr[kk], b0, acc0, 0, 0, 0);
            acc1 = __builtin_amdgcn_mfma_f32_16x16x32_bf16(afr[kk], b1, acc1, 0, 0, 0);
        }
        #pragma unroll
        for (int r = 0; r < 4; r++) {
            gates[w * 16 + quad * 4 + r][col]      = acc0[r];
            gates[w * 16 + quad * 4 + r][16 + col] = acc1[r];
        }
        __syncthreads();

        // postprocess: thread t handles (m = t>>2, j = 2*(t&3), 2*(t&3)+1);
        // packs the h pair into one coherent u32 store.
        {
            int m  = t >> 2;
            int j0 = (t & 3) * 2;
            int j1 = j0 + 1;
            float iv0 = sigm(gates[m][j0]      + bias[j0]);
            float fv0 = sigm(gates[m][8 + j0]  + bias[8 + j0]);
            float gv0 = tanh_fast(gates[m][16 + j0] + bias[16 + j0]);
            float ov0 = sigm(gates[m][24 + j0] + bias[24 + j0]);
            float iv1 = sigm(gates[m][j1]      + bias[j1]);
            float fv1 = sigm(gates[m][8 + j1]  + bias[8 + j1]);
            float gv1 = tanh_fast(gates[m][16 + j1] + bias[16 + j1]);
            float ov1 = sigm(gates[m][24 + j1] + bias[24 + j1]);
            float c0 = fv0 * cst[m][j0] + iv0 * gv0;
            float c1 = fv1 * cst[m][j1] + iv1 * gv1;
            cst[m][j0] = c0;
            cst[m][j1] = c1;
            float h0 = ov0 * tanh_fast(c0);
            float h1 = ov1 * tanh_fast(c1);
            uint32_t pack = (uint32_t)(uint16_t)f2bf(h0)
                          | ((uint32_t)(uint16_t)f2bf(h1) << 16);
            size_t widx = ((size_t)(step + 1) * (BATCH * HID)
                         + (size_t)m * HID + g * 8 + j0) >> 1;
            __hip_atomic_store((uint32_t*)hbuf + widx, pack,
                               __ATOMIC_RELAXED, __HIP_MEMORY_SCOPE_AGENT);
        }
        // barrier lowers with vmcnt(0): all 256 threads' coherent h-stores
        // have completed at the coherent point before t0 publishes.
        __syncthreads();

        if (t == 0)
            __hip_atomic_fetch_add(&cnt[step + 1], 1,
                                   __ATOMIC_RELAXED, __HIP_MEMORY_SCOPE_AGENT);
    }
}

// ---------------------------------------------------------------------------
// K3: logits = h_seq * W_fc^T + b_fc -> log_softmax(18). One token per thread.
// ---------------------------------------------------------------------------
__global__ __launch_bounds__(256) void k3_logits(
    const short* __restrict__ hbuf, const void* __restrict__ w_fc,
    const void* __restrict__ b_fc, const void* __restrict__ emb,
    void* __restrict__ out)
{
    __shared__ float Wf[NOUT][516];
    const bool isbf = detect_bf16(emb);
    const int t = threadIdx.x;
    for (int idx = t; idx < NOUT * 64; idx += 256) {
        int o = idx >> 6, ch = (idx & 63) * 8;
        #pragma unroll
        for (int j = 0; j < 8; j++)
            Wf[o][ch + j] = rd(w_fc, o * HID + ch + j, isbf);
    }
    __syncthreads();

    int u = blockIdx.x * 256 + t;              // u = s*64+b
    const short* hp = hbuf + (size_t)(u + BATCH) * HID;

    float acc[NOUT];
    #pragma unroll
    for (int o = 0; o < NOUT; o++) acc[o] = rd(b_fc, o, isbf);

    for (int ch = 0; ch < HID; ch += 8) {
        bf16x8 h8 = *(const bf16x8*)(hp + ch);
        float hf[8];
        #pragma unroll
        for (int j = 0; j < 8; j++) hf[j] = bf2f(h8[j]);
        #pragma unroll
        for (int o = 0; o < NOUT; o++) {
            floatx4 wa = *(const floatx4*)&Wf[o][ch];
            floatx4 wb = *(const floatx4*)&Wf[o][ch + 4];
            acc[o] += hf[0] * wa[0] + hf[1] * wa[1] + hf[2] * wa[2] + hf[3] * wa[3]
                    + hf[4] * wb[0] + hf[5] * wb[1] + hf[6] * wb[2] + hf[7] * wb[3];
        }
    }

    float mx = acc[0];
    #pragma unroll
    for (int o = 1; o < NOUT; o++) mx = fmaxf(mx, acc[o]);
    float s = 0.f;
    #pragma unroll
    for (int o = 0; o < NOUT; o++) s += __expf(acc[o] - mx);
    float lse = mx + __logf(s);

    int b = u & 63, sq = u >> 6;
    size_t base = (size_t)b * (SEQ * NOUT) + (size_t)sq * NOUT;
    if (isbf) {
        short* op = (short*)out + base;
        #pragma unroll
        for (int o = 0; o < NOUT; o++) op[o] = f2bf(acc[o] - lse);
    } else {
        float* op = (float*)out + base;
        #pragma unroll
        for (int o = 0; o < NOUT; o++) op[o] = acc[o] - lse;
    }
}

// ---------------------------------------------------------------------------
extern "C" void kernel_launch(void* const* d_in, const int* in_sizes, int n_in,
                              void* d_out, int out_size, void* d_ws, size_t ws_size,
                              hipStream_t stream) {
    const int*  x   = (const int*)d_in[0];
    const void* emb = d_in[1];
    const void* wih = d_in[2];
    const void* whh = d_in[3];
    const void* bih = d_in[4];
    const void* bhh = d_in[5];
    const void* wfc = d_in[6];
    const void* bfc = d_in[7];

    char*  ws   = (char*)d_ws;
    int*   cnt  = (int*)ws;
    short* hbuf = (short*)(ws + 4096);
    short* eseq = (short*)(ws + 4096 + (size_t)(SEQ + 1) * BATCH * HID * 2);

    (void)hipMemsetAsync(cnt, 0, 4096, stream);                     // cnt[] = 0
    (void)hipMemsetAsync(hbuf, 0, (size_t)BATCH * HID * 2, stream); // h_0 = 0

    k0_gather<<<1024, 256, 0, stream>>>(x, emb, eseq);
    k2_lstm<<<64, 256, 0, stream>>>(whh, wih, bih, bhh, emb, eseq, hbuf, cnt);
    k3_logits<<<128, 256, 0, stream>>>(hbuf, wfc, bfc, emb, d_out);
}